// Round 5
// baseline (786.659 us; speedup 1.0000x reference)
//
#include <hip/hip_runtime.h>

#define VOCAB_ROWS 50001
#define EMB 32
#define UNITS 16
#define GATES 48
#define BATCH 256
#define SEQ 4096

// ---------------- Phase 1: per-vocab projection table ----------------
// proj[v][j] = bias[0][j] + sum_e emb[v][e] * kernel[e][j]
__global__ __launch_bounds__(256) void proj_kernel(const float* __restrict__ emb,
                                                   const float* __restrict__ kern,
                                                   const float* __restrict__ bias,
                                                   float* __restrict__ proj) {
    int gid = blockIdx.x * 256 + threadIdx.x;
    if (gid >= VOCAB_ROWS * GATES) return;
    int v = gid / GATES;
    int j = gid - v * GATES;
    const float4* e4 = (const float4*)(emb + v * EMB);   // emb rows are 128B, 16B-aligned
    float acc = bias[j];
#pragma unroll
    for (int e = 0; e < EMB / 4; ++e) {
        float4 ev = e4[e];
        acc = fmaf(ev.x, kern[(4 * e + 0) * GATES + j], acc);
        acc = fmaf(ev.y, kern[(4 * e + 1) * GATES + j], acc);
        acc = fmaf(ev.z, kern[(4 * e + 2) * GATES + j], acc);
        acc = fmaf(ev.w, kern[(4 * e + 3) * GATES + j], acc);
    }
    proj[gid] = acc;
}

// ---------------- Phase 2: sequential GRU scan ----------------
__device__ __forceinline__ float sigf(float x) {
    float e = __expf(-x);
    return __builtin_amdgcn_rcpf(1.0f + e);
}

__device__ __forceinline__ float rdlane(float v, int l) {
    return __int_as_float(__builtin_amdgcn_readlane(__float_as_int(v), l));
}

// gfx950 VALU cross-lane half-swaps via the OFFICIAL builtins (returns the
// {vdst,vsrc} pair) -- prior rounds' hand-rolled inline asm broke under any
// register-allocation perturbation; builtins give the compiler full dataflow.
// Direction (which output carries hi-half -> lo-lanes) probed at runtime once.
typedef unsigned u32x2 __attribute__((ext_vector_type(2)));

__device__ __forceinline__ float swap32_hi(float y, bool selB) {
    u32x2 r = __builtin_amdgcn_permlane32_swap(__float_as_uint(y), __float_as_uint(y),
                                               false, false);
    return __uint_as_float(selB ? r[1] : r[0]);
}
__device__ __forceinline__ float swap16_hi(float y, bool selB) {
    u32x2 r = __builtin_amdgcn_permlane16_swap(__float_as_uint(y), __float_as_uint(y),
                                               false, false);
    return __uint_as_float(selB ? r[1] : r[0]);
}

// Column-per-lane layout: lane j in [0,48) owns gate column j of the 16x48
// matvec (z: 0-15, r: 16-31, h: 32-47); lanes 48-63 mirror 32-47.
// h state lives in lanes 0-15. Per step: 16 readlane + 16 FMA + 1 gather.
//
// NO __restrict__ on gru_scan pointers (deliberate): with const+restrict the
// reck loads are invariant-marked -> LLVM remats them INSIDE the serial loop
// instead of keeping R[16] live (VGPR_Count=24 < ~36 live, no scratch traffic
// => remat, ~50 extra instrs/step un-hidable at 1 wave/SIMD). Without noalias
// the loads are not remat candidates; the loop body has no stores, so load
// scheduling/prefetch depth is unaffected.
__global__ __launch_bounds__(64, 1) void gru_scan(const int* ids,
                                                  const float* reck,
                                                  const float* bias,
                                                  const float* proj,
                                                  float* out) {
    const int lane = threadIdx.x & 63;
    const int j    = (lane < 48) ? lane : lane - 16;   // owned gate column
    const int b    = blockIdx.x;                       // one batch row per wave
    const int* idrow = ids + (size_t)b * SEQ;

    // probe swap output-order once (wave-uniform booleans)
    bool selB32, selB16;
    {
        unsigned li = __float_as_uint((float)lane);
        u32x2 p32 = __builtin_amdgcn_permlane32_swap(li, li, false, false);
        selB32 = (rdlane(__uint_as_float(p32[1]), 0) == 32.0f);
        u32x2 p16 = __builtin_amdgcn_permlane16_swap(li, li, false, false);
        selB16 = (rdlane(__uint_as_float(p16[1]), 0) == 16.0f);
    }

    // recurrent weight column j (16-deep) + recurrent bias
    float R[UNITS];
#pragma unroll
    for (int k = 0; k < UNITS; ++k) R[k] = reck[k * GATES + j];
    const float bj = bias[GATES + j];
    const unsigned offv = (unsigned)j;                 // word offset in proj row

    // software-pipeline rings: x column 8 ahead, ids 16 ahead
    float xq[8];
    int   idq[8];
#pragma unroll
    for (int s = 0; s < 8; ++s) {
        int id0 = idrow[s];
        xq[s]  = proj[(unsigned)(id0 * GATES) + offv];
        idq[s] = idrow[8 + s];
    }

    float h = 0.0f;                                    // valid in lanes 0-15
    for (int t0 = 0; t0 < SEQ; t0 += 8) {
#pragma unroll
        for (int uu = 0; uu < 8; ++uu) {
            const int t = t0 + uu;
            const float x = xq[uu];                    // lane j's proj value (has input bias)
            // prefetch: row for t+8 (id loaded 8 steps ago), id for t+16
            const int id8 = idq[uu];
            int tf = t + 16;
            tf = tf < SEQ ? tf : SEQ - 1;
            idq[uu] = idrow[tf];
            xq[uu]  = proj[(unsigned)(id8 * GATES) + offv];

            // a_j = b1[j] + sum_k R[k][j] * h[k]   (h broadcast via readlane/SGPR)
            float aa = bj, ab = 0.0f;
#pragma unroll
            for (int k = 0; k < 8; ++k) {
                const float ha = rdlane(h, k);
                const float hb = rdlane(h, k + 8);
                aa = fmaf(R[k],     ha, aa);
                ab = fmaf(R[k + 8], hb, ab);
            }
            const float a = aa + ab;
            const float y = sigf(x + a);               // z (lanes 0-15), r (16-31)

            // deliver r, ah(=recurrent h incl bias), xh into lanes 0-15
            const float rt = swap16_hi(y, selB16);     // r from lane+16
            const float at = swap32_hi(a, selB32);     // recurrent h-part from lane+32
            const float xt = swap32_hi(x, selB32);     // xh from lane+32

            const float hh = sigf(fmaf(rt, at, xt));   // sigmoid(xh + r*rh)
            h = fmaf(y, h - hh, hh);                   // z*h + (1-z)*hh
        }
    }

    if (lane < UNITS) out[b * UNITS + lane] = h;
}

extern "C" void kernel_launch(void* const* d_in, const int* in_sizes, int n_in,
                              void* d_out, int out_size, void* d_ws, size_t ws_size,
                              hipStream_t stream) {
    const int*   ids  = (const int*)d_in[0];
    const float* emb  = (const float*)d_in[1];
    const float* kern = (const float*)d_in[2];
    const float* reck = (const float*)d_in[3];
    const float* bias = (const float*)d_in[4];
    float* out  = (float*)d_out;
    float* proj = (float*)d_ws;   // 50001*48 floats = 9.6 MB scratch

    const int total = VOCAB_ROWS * GATES;
    proj_kernel<<<(total + 255) / 256, 256, 0, stream>>>(emb, kern, bias, proj);
    gru_scan<<<BATCH, 64, 0, stream>>>(ids, reck, bias, proj, out);
}

// Round 6
// 577.670 us; speedup vs baseline: 1.3618x; 1.3618x over previous
//
#include <hip/hip_runtime.h>

#define VOCAB_ROWS 50001
#define EMB 32
#define UNITS 16
#define GATES 48
#define BATCH 256
#define SEQ 4096

// ---------------- Phase 1: per-vocab projection table ----------------
// proj[v][j] = bias[0][j] + sum_e emb[v][e] * kernel[e][j]
__global__ __launch_bounds__(256) void proj_kernel(const float* __restrict__ emb,
                                                   const float* __restrict__ kern,
                                                   const float* __restrict__ bias,
                                                   float* __restrict__ proj) {
    int gid = blockIdx.x * 256 + threadIdx.x;
    if (gid >= VOCAB_ROWS * GATES) return;
    int v = gid / GATES;
    int j = gid - v * GATES;
    const float4* e4 = (const float4*)(emb + v * EMB);   // emb rows are 128B, 16B-aligned
    float acc = bias[j];
#pragma unroll
    for (int e = 0; e < EMB / 4; ++e) {
        float4 ev = e4[e];
        acc = fmaf(ev.x, kern[(4 * e + 0) * GATES + j], acc);
        acc = fmaf(ev.y, kern[(4 * e + 1) * GATES + j], acc);
        acc = fmaf(ev.z, kern[(4 * e + 2) * GATES + j], acc);
        acc = fmaf(ev.w, kern[(4 * e + 3) * GATES + j], acc);
    }
    proj[gid] = acc;
}

// ---------------- Phase 2: sequential GRU scan ----------------
__device__ __forceinline__ float sigf(float x) {
    float e = __expf(-x);
    return __builtin_amdgcn_rcpf(1.0f + e);
}

__device__ __forceinline__ float rdlane(float v, int l) {
    return __int_as_float(__builtin_amdgcn_readlane(__float_as_int(v), l));
}

// gfx950 VALU cross-lane half-swaps via builtins (R5-verified correct; the
// hand-rolled asm versions broke under register-allocation perturbation).
typedef unsigned u32x2 __attribute__((ext_vector_type(2)));

__device__ __forceinline__ float swap32_hi(float y, bool selB) {
    u32x2 r = __builtin_amdgcn_permlane32_swap(__float_as_uint(y), __float_as_uint(y),
                                               false, false);
    return __uint_as_float(selB ? r[1] : r[0]);
}
__device__ __forceinline__ float swap16_hi(float y, bool selB) {
    u32x2 r = __builtin_amdgcn_permlane16_swap(__float_as_uint(y), __float_as_uint(y),
                                               false, false);
    return __uint_as_float(selB ? r[1] : r[0]);
}

// One GRU step; arithmetic byte-identical to the R5 passing body.
#define GRU_STEP(XV) do {                                              \
    const float x_ = (XV);                                             \
    float aa = bj, ab = 0.0f;                                          \
    _Pragma("unroll")                                                  \
    for (int k = 0; k < 8; ++k) {                                      \
        const float ha = rdlane(h, k);                                 \
        const float hb = rdlane(h, k + 8);                             \
        aa = fmaf(R[k],     ha, aa);                                   \
        ab = fmaf(R[k + 8], hb, ab);                                   \
    }                                                                  \
    const float a_ = aa + ab;                                          \
    const float y_ = sigf(x_ + a_);                                    \
    const float rt = swap16_hi(y_, selB16);                            \
    const float at = swap32_hi(a_, selB32);                            \
    const float xt = swap32_hi(x_, selB32);                            \
    const float hh = sigf(fmaf(rt, at, xt));                           \
    h = fmaf(y_, h - hh, hh);                                          \
} while (0)

// Clustered 8-wide gather refill: 2 ds_read_b128 of consecutive ids (LDS,
// uniform addr -> broadcast) + 8 gathers issued back-to-back.
#define REFILL(BUF, BASE) do {                                         \
    const int4* lp_ = (const int4*)(lids + (BASE));                    \
    const int4 c0_ = lp_[0], c1_ = lp_[1];                             \
    BUF[0] = proj[(unsigned)c0_.x * 48u + offv];                       \
    BUF[1] = proj[(unsigned)c0_.y * 48u + offv];                       \
    BUF[2] = proj[(unsigned)c0_.z * 48u + offv];                       \
    BUF[3] = proj[(unsigned)c0_.w * 48u + offv];                       \
    BUF[4] = proj[(unsigned)c1_.x * 48u + offv];                       \
    BUF[5] = proj[(unsigned)c1_.y * 48u + offv];                       \
    BUF[6] = proj[(unsigned)c1_.z * 48u + offv];                       \
    BUF[7] = proj[(unsigned)c1_.w * 48u + offv];                       \
} while (0)

// Column-per-lane layout: lane j in [0,48) owns gate column j of the 16x48
// matvec (z: 0-15, r: 16-31, h: 32-47); lanes 48-63 mirror 32-47.
// h state lives in lanes 0-15.
//
// Memory-wait structure (this round's change): ids live in LDS (loaded once,
// removes the per-step id global-load from the vmcnt stream + the tail clamp);
// proj gathers are double-buffered in xa/xb with loads CLUSTERED per 8-step
// half-block. Consuming xa needs one counted s_waitcnt vmcnt(8) (the 8 xb
// loads just issued) instead of 8 per-step waits over a 16-deep mixed window;
// prefetch distance stays 8-16 steps (>> L3-hit latency).
__global__ __launch_bounds__(64, 1) void gru_scan(const int* __restrict__ ids,
                                                  const float* __restrict__ reck,
                                                  const float* __restrict__ bias,
                                                  const float* __restrict__ proj,
                                                  float* __restrict__ out) {
    const int lane = threadIdx.x & 63;
    const int j    = (lane < 48) ? lane : lane - 16;   // owned gate column
    const int b    = blockIdx.x;                       // one batch row per wave
    const int* __restrict__ idrow = ids + (size_t)b * SEQ;

    __shared__ int lids[SEQ + 16];
    {
        const int4* gsrc = (const int4*)idrow;         // 16KB-aligned row
        int4* ldst = (int4*)lids;
#pragma unroll
        for (int i = 0; i < SEQ / 4 / 64; ++i)         // 16 iters, coalesced
            ldst[lane + i * 64] = gsrc[lane + i * 64];
        if (lane < 16) lids[SEQ + lane] = idrow[SEQ - 1];   // tail pad
    }
    __syncthreads();

    // probe swap output-order once (wave-uniform booleans)
    bool selB32, selB16;
    {
        unsigned li = __float_as_uint((float)lane);
        u32x2 p32 = __builtin_amdgcn_permlane32_swap(li, li, false, false);
        selB32 = (rdlane(__uint_as_float(p32[1]), 0) == 32.0f);
        u32x2 p16 = __builtin_amdgcn_permlane16_swap(li, li, false, false);
        selB16 = (rdlane(__uint_as_float(p16[1]), 0) == 16.0f);
    }

    // recurrent weight column j (16-deep) + recurrent bias
    float R[UNITS];
#pragma unroll
    for (int k = 0; k < UNITS; ++k) R[k] = reck[k * GATES + j];
    const float bj = bias[GATES + j];
    const unsigned offv = (unsigned)j;                 // word offset in proj row

    // prologue: xa = steps 0..7, xb = steps 8..15
    float xa[8], xb[8];
    REFILL(xa, 0);
    REFILL(xb, 8);

    float h = 0.0f;                                    // valid in lanes 0-15
    for (int t0 = 0; t0 < SEQ; t0 += 16) {
        // consume xa (steps t0..t0+7), then refill xa for steps t0+16..t0+23
#pragma unroll
        for (int uu = 0; uu < 8; ++uu) GRU_STEP(xa[uu]);
        REFILL(xa, t0 + 16);
        // consume xb (steps t0+8..t0+15), then refill xb for t0+24..t0+31
#pragma unroll
        for (int uu = 0; uu < 8; ++uu) GRU_STEP(xb[uu]);
        REFILL(xb, t0 + 24);
    }

    if (lane < UNITS) out[b * UNITS + lane] = h;
}

extern "C" void kernel_launch(void* const* d_in, const int* in_sizes, int n_in,
                              void* d_out, int out_size, void* d_ws, size_t ws_size,
                              hipStream_t stream) {
    const int*   ids  = (const int*)d_in[0];
    const float* emb  = (const float*)d_in[1];
    const float* kern = (const float*)d_in[2];
    const float* reck = (const float*)d_in[3];
    const float* bias = (const float*)d_in[4];
    float* out  = (float*)d_out;
    float* proj = (float*)d_ws;   // 50001*48 floats = 9.6 MB scratch

    const int total = VOCAB_ROWS * GATES;
    proj_kernel<<<(total + 255) / 256, 256, 0, stream>>>(emb, kern, bias, proj);
    gru_scan<<<BATCH, 64, 0, stream>>>(ids, reck, bias, proj, out);
}

// Round 7
// 571.337 us; speedup vs baseline: 1.3769x; 1.0111x over previous
//
#include <hip/hip_runtime.h>

#define VOCAB_ROWS 50001
#define EMB 32
#define UNITS 16
#define GATES 48
#define BATCH 256
#define SEQ 4096

// -log2(e): all gate pre-activations are prescaled by this so that
// sigmoid(t) == rcp(1 + exp2(v)) with v = -log2e * t  (removes the per-sigmoid
// v_mul from the serial chain; exp2 is the native v_exp_f32 op).
#define NEGLOG2E (-1.4426950408889634f)

#if __has_builtin(__builtin_amdgcn_exp2f)
#define EXP2F(x) __builtin_amdgcn_exp2f(x)
#else
#define EXP2F(x) exp2f(x)
#endif

// ---------------- Phase 1: per-vocab projection table (prescaled) ----------
// proj[v][j] = NEGLOG2E * (bias[0][j] + sum_e emb[v][e] * kernel[e][j])
__global__ __launch_bounds__(256) void proj_kernel(const float* __restrict__ emb,
                                                   const float* __restrict__ kern,
                                                   const float* __restrict__ bias,
                                                   float* __restrict__ proj) {
    int gid = blockIdx.x * 256 + threadIdx.x;
    if (gid >= VOCAB_ROWS * GATES) return;
    int v = gid / GATES;
    int j = gid - v * GATES;
    const float4* e4 = (const float4*)(emb + v * EMB);   // emb rows are 128B, 16B-aligned
    float acc = bias[j];
#pragma unroll
    for (int e = 0; e < EMB / 4; ++e) {
        float4 ev = e4[e];
        acc = fmaf(ev.x, kern[(4 * e + 0) * GATES + j], acc);
        acc = fmaf(ev.y, kern[(4 * e + 1) * GATES + j], acc);
        acc = fmaf(ev.z, kern[(4 * e + 2) * GATES + j], acc);
        acc = fmaf(ev.w, kern[(4 * e + 3) * GATES + j], acc);
    }
    proj[gid] = acc * NEGLOG2E;
}

// ---------------- Phase 2: sequential GRU scan ----------------
__device__ __forceinline__ float rdlane(float v, int l) {
    return __int_as_float(__builtin_amdgcn_readlane(__float_as_int(v), l));
}

// gfx950 VALU cross-lane half-swaps via builtins (R5/R6-verified correct).
// Output order (which result carries hi-half -> lo-lanes) probed at runtime;
// SB template param makes the select compile-time in the 4 loop variants.
typedef unsigned u32x2 __attribute__((ext_vector_type(2)));

template <bool SB>
__device__ __forceinline__ float swap32t(float y) {
    u32x2 r = __builtin_amdgcn_permlane32_swap(__float_as_uint(y), __float_as_uint(y),
                                               false, false);
    return __uint_as_float(SB ? r[1] : r[0]);
}
template <bool SB>
__device__ __forceinline__ float swap16t(float y) {
    u32x2 r = __builtin_amdgcn_permlane16_swap(__float_as_uint(y), __float_as_uint(y),
                                               false, false);
    return __uint_as_float(SB ? r[1] : r[0]);
}

// One GRU step (prescaled domain). 4x4 FMA split shortens the serial chain;
// p/q computed before hh so only one fma follows the second sigmoid.
#define GRU_STEP(XV) do {                                              \
    const float x_ = (XV);                                             \
    float a0 = bj, a1 = 0.f, a2 = 0.f, a3 = 0.f;                       \
    _Pragma("unroll")                                                  \
    for (int k = 0; k < 4; ++k) {                                      \
        a0 = fmaf(R[k],      rdlane(h, k),      a0);                   \
        a1 = fmaf(R[k + 4],  rdlane(h, k + 4),  a1);                   \
        a2 = fmaf(R[k + 8],  rdlane(h, k + 8),  a2);                   \
        a3 = fmaf(R[k + 12], rdlane(h, k + 12), a3);                   \
    }                                                                  \
    const float a_ = (a0 + a1) + (a2 + a3);                           \
    const float y_ = __builtin_amdgcn_rcpf(1.0f + EXP2F(x_ + a_));     \
    const float rt = swap16t<SB16>(y_);                                \
    const float at = swap32t<SB32>(a_);                                \
    const float xt = swap32t<SB32>(x_);                                \
    const float p_ = y_ * h;                                           \
    const float q_ = 1.0f - y_;                                        \
    const float hh = __builtin_amdgcn_rcpf(1.0f + EXP2F(fmaf(rt, at, xt))); \
    h = fmaf(q_, hh, p_);                                              \
} while (0)

// Clustered 8-wide gather refill: 2 ds_read_b128 of consecutive ids (LDS,
// uniform addr -> broadcast) + 8 gathers issued back-to-back.
#define REFILL(BUF, BASE) do {                                         \
    const int4* lp_ = (const int4*)(lids + (BASE));                    \
    const int4 c0_ = lp_[0], c1_ = lp_[1];                             \
    BUF[0] = proj[(unsigned)c0_.x * 48u + offv];                       \
    BUF[1] = proj[(unsigned)c0_.y * 48u + offv];                       \
    BUF[2] = proj[(unsigned)c0_.z * 48u + offv];                       \
    BUF[3] = proj[(unsigned)c0_.w * 48u + offv];                       \
    BUF[4] = proj[(unsigned)c1_.x * 48u + offv];                       \
    BUF[5] = proj[(unsigned)c1_.y * 48u + offv];                       \
    BUF[6] = proj[(unsigned)c1_.z * 48u + offv];                       \
    BUF[7] = proj[(unsigned)c1_.w * 48u + offv];                       \
} while (0)

// Column-per-lane layout: lane j in [0,48) owns gate column j of the 16x48
// matvec (z: 0-15, r: 16-31, h: 32-47); lanes 48-63 mirror 32-47.
// h state lives in lanes 0-15. ids in LDS; proj gathers double-buffered with
// clustered loads (one counted vmcnt wait per 8 steps) -- R6-verified.
template <bool SB32, bool SB16>
__device__ __forceinline__ void scan_body(const int* __restrict__ lids,
                                          const float* __restrict__ reck,
                                          const float* __restrict__ bias,
                                          const float* __restrict__ proj,
                                          float* __restrict__ out,
                                          int lane, int j, int b) {
    // recurrent weight column j (16-deep) + recurrent bias, prescaled
    float R[UNITS];
#pragma unroll
    for (int k = 0; k < UNITS; ++k) R[k] = reck[k * GATES + j] * NEGLOG2E;
    const float bj = bias[GATES + j] * NEGLOG2E;
    const unsigned offv = (unsigned)j;                 // word offset in proj row

    // prologue: xa = steps 0..7, xb = steps 8..15
    float xa[8], xb[8];
    REFILL(xa, 0);
    REFILL(xb, 8);

    float h = 0.0f;                                    // valid in lanes 0-15
    for (int t0 = 0; t0 < SEQ; t0 += 16) {
#pragma unroll
        for (int uu = 0; uu < 8; ++uu) GRU_STEP(xa[uu]);
        REFILL(xa, t0 + 16);
#pragma unroll
        for (int uu = 0; uu < 8; ++uu) GRU_STEP(xb[uu]);
        REFILL(xb, t0 + 24);
    }

    if (lane < UNITS) out[b * UNITS + lane] = h;
}

__global__ __launch_bounds__(64, 1) void gru_scan(const int* __restrict__ ids,
                                                  const float* __restrict__ reck,
                                                  const float* __restrict__ bias,
                                                  const float* __restrict__ proj,
                                                  float* __restrict__ out) {
    const int lane = threadIdx.x & 63;
    const int j    = (lane < 48) ? lane : lane - 16;   // owned gate column
    const int b    = blockIdx.x;                       // one batch row per wave
    const int* __restrict__ idrow = ids + (size_t)b * SEQ;

    __shared__ int lids[SEQ + 16];
    {
        const int4* gsrc = (const int4*)idrow;         // 16KB-aligned row
        int4* ldst = (int4*)lids;
#pragma unroll
        for (int i = 0; i < SEQ / 4 / 64; ++i)         // 16 iters, coalesced
            ldst[lane + i * 64] = gsrc[lane + i * 64];
        if (lane < 16) lids[SEQ + lane] = idrow[SEQ - 1];   // tail pad
    }
    __syncthreads();

    // probe swap output-order once (wave-uniform), then run a fully
    // specialized loop (removes per-step v_cndmask selects)
    bool selB32, selB16;
    {
        unsigned li = __float_as_uint((float)lane);
        u32x2 p32 = __builtin_amdgcn_permlane32_swap(li, li, false, false);
        selB32 = (rdlane(__uint_as_float(p32[1]), 0) == 32.0f);
        u32x2 p16 = __builtin_amdgcn_permlane16_swap(li, li, false, false);
        selB16 = (rdlane(__uint_as_float(p16[1]), 0) == 16.0f);
    }

    if (selB32) {
        if (selB16) scan_body<true,  true >(lids, reck, bias, proj, out, lane, j, b);
        else        scan_body<true,  false>(lids, reck, bias, proj, out, lane, j, b);
    } else {
        if (selB16) scan_body<false, true >(lids, reck, bias, proj, out, lane, j, b);
        else        scan_body<false, false>(lids, reck, bias, proj, out, lane, j, b);
    }
}

extern "C" void kernel_launch(void* const* d_in, const int* in_sizes, int n_in,
                              void* d_out, int out_size, void* d_ws, size_t ws_size,
                              hipStream_t stream) {
    const int*   ids  = (const int*)d_in[0];
    const float* emb  = (const float*)d_in[1];
    const float* kern = (const float*)d_in[2];
    const float* reck = (const float*)d_in[3];
    const float* bias = (const float*)d_in[4];
    float* out  = (float*)d_out;
    float* proj = (float*)d_ws;   // 50001*48 floats = 9.6 MB scratch

    const int total = VOCAB_ROWS * GATES;
    proj_kernel<<<(total + 255) / 256, 256, 0, stream>>>(emb, kern, bias, proj);
    gru_scan<<<BATCH, 64, 0, stream>>>(ids, reck, bias, proj, out);
}